// Round 1
// baseline (223.923 us; speedup 1.0000x reference)
//
#include <hip/hip_runtime.h>
#include <hip/hip_bf16.h>
#include <math.h>

// Problem constants: B=2, C=256, H=W=64 -> HW=4096
#define BB 2
#define CC 256
#define HWN 4096
#define PT 32              // pixels per prep block

typedef __attribute__((ext_vector_type(8))) __bf16 bf16x8;
typedef __attribute__((ext_vector_type(4))) float floatx4;

__device__ __forceinline__ unsigned short f2bf(float f) {
    union { float f; unsigned u; } v; v.f = f;
    unsigned r = v.u + 0x7FFF + ((v.u >> 16) & 1);   // round-to-nearest-even
    return (unsigned short)(r >> 16);
}

__device__ __forceinline__ float bf2f(unsigned short h) {
    union { unsigned u; float f; } v; v.u = ((unsigned)h) << 16;
    return v.f;
}

// acc[0]=kp_sum, acc[1]=desc_sum, acc[2]=match_sum
__global__ void zero_acc_kernel(float* acc) {
    if (threadIdx.x < 4) acc[threadIdx.x] = 0.0f;
}

// One block per (batch, 32-pixel chunk). Computes per-pixel channel norms,
// writes A=norm(dv), D=norm(df)-norm(di) transposed to [b][p][c] bf16
// (K-contiguous for MFMA). Also fuses desc-loss and kp-loss partial sums.
__global__ __launch_bounds__(256) void prep_kernel(
    const float* __restrict__ sv, const float* __restrict__ si,
    const float* __restrict__ sf, const float* __restrict__ dv,
    const float* __restrict__ di, const float* __restrict__ df,
    unsigned short* __restrict__ Abf, unsigned short* __restrict__ Dbf,
    float* __restrict__ acc)
{
    __shared__ unsigned short lv[PT][CC];  // 16 KB each; 48 KB total
    __shared__ unsigned short li[PT][CC];
    __shared__ unsigned short lf[PT][CC];
    __shared__ float ssq[3][PT];
    __shared__ float inv[3][PT];

    const int b   = blockIdx.x / (HWN / PT);
    const int p0  = (blockIdx.x % (HWN / PT)) * PT;
    const int tid = threadIdx.x;
    const int tp  = tid & (PT - 1);   // pixel within chunk
    const int cs  = tid >> 5;         // channel subgroup 0..7

    if (tid < 3 * PT) ((float*)ssq)[tid] = 0.0f;
    __syncthreads();

    float sqv = 0.f, sqi = 0.f, sqf = 0.f, descp = 0.f;
    const size_t base = (size_t)b * CC * HWN + p0 + tp;
    #pragma unroll 4
    for (int j = 0; j < 32; ++j) {
        const int c = cs * 32 + j;
        const size_t idx = base + (size_t)c * HWN;   // coalesced along tp
        const float v = dv[idx], ii = di[idx], ff = df[idx];
        descp += fabsf(ff - 0.5f * (v + ii));
        sqv += v * v; sqi += ii * ii; sqf += ff * ff;
        lv[tp][c] = f2bf(v); li[tp][c] = f2bf(ii); lf[tp][c] = f2bf(ff);
    }
    atomicAdd(&ssq[0][tp], sqv);
    atomicAdd(&ssq[1][tp], sqi);
    atomicAdd(&ssq[2][tp], sqf);

    // desc partial: wave reduce, one atomic per wave
    #pragma unroll
    for (int off = 32; off > 0; off >>= 1) descp += __shfl_down(descp, off);
    if ((tid & 63) == 0) atomicAdd(&acc[1], descp);

    // kp term: this block's 32 pixels (wave 0 only)
    if (tid < 64) {
        float kpv = 0.f;
        if (tid < PT) {
            const size_t sidx = (size_t)b * HWN + p0 + tid;
            kpv = fabsf(sf[sidx] - fmaxf(sv[sidx], si[sidx]));
        }
        #pragma unroll
        for (int off = 32; off > 0; off >>= 1) kpv += __shfl_down(kpv, off);
        if (tid == 0) atomicAdd(&acc[0], kpv);
    }
    __syncthreads();

    if (tid < 3 * PT) {
        const float s = ((float*)ssq)[tid];
        ((float*)inv)[tid] = 1.0f / fmaxf(sqrtf(s), 1e-12f);
    }
    __syncthreads();

    // Write phase: per pixel row, 256 threads cover the 256 channels
    // -> 512B contiguous bf16 stores (coalesced).
    for (int p = 0; p < PT; ++p) {
        const size_t orow = ((size_t)b * HWN + p0 + p) * CC + tid;
        const float a = bf2f(lv[p][tid]) * inv[0][p];
        const float d = bf2f(lf[p][tid]) * inv[2][p] - bf2f(li[p][tid]) * inv[1][p];
        Abf[orow] = f2bf(a);
        Dbf[orow] = f2bf(d);
    }
}

// Per batch: S = A_rows · D_rows^T over K=256 (both stored [row][k] bf16).
// Block = 128x128 tile, 4 waves in 2x2, each wave 4x4 MFMA 16x16x32 tiles.
// Epilogue: sum |S| (invariant to C/D layout permutation) -> atomicAdd.
__global__ __launch_bounds__(256) void gemm_abs_kernel(
    const unsigned short* __restrict__ Abf,
    const unsigned short* __restrict__ Dbf,
    float* __restrict__ acc)
{
    const int b    = blockIdx.z;
    const int bm   = blockIdx.x * 128;
    const int bn   = blockIdx.y * 128;
    const int tid  = threadIdx.x;
    const int wave = tid >> 6;
    const int lane = tid & 63;
    const int wr   = wave >> 1, wc = wave & 1;

    const bf16x8* A = (const bf16x8*)(Abf + (size_t)b * HWN * CC);
    const bf16x8* D = (const bf16x8*)(Dbf + (size_t)b * HWN * CC);
    // row stride in bf16x8 units = CC/8 = 32
    const int mrow = bm + wr * 64 + (lane & 15);
    const int nrow = bn + wc * 64 + (lane & 15);
    const int kof  = lane >> 4;   // k-chunk of 8 elements

    floatx4 accf[4][4];
    #pragma unroll
    for (int mi = 0; mi < 4; ++mi)
        #pragma unroll
        for (int ni = 0; ni < 4; ++ni)
            accf[mi][ni] = (floatx4){0.f, 0.f, 0.f, 0.f};

    #pragma unroll
    for (int k8 = 0; k8 < 32; k8 += 4) {   // K=256 in steps of 32 (4 bf16x8 units)
        bf16x8 af[4], bfm[4];
        #pragma unroll
        for (int i = 0; i < 4; ++i)
            af[i] = A[(size_t)(mrow + i * 16) * 32 + k8 + kof];
        #pragma unroll
        for (int i = 0; i < 4; ++i)
            bfm[i] = D[(size_t)(nrow + i * 16) * 32 + k8 + kof];
        #pragma unroll
        for (int mi = 0; mi < 4; ++mi)
            #pragma unroll
            for (int ni = 0; ni < 4; ++ni)
                accf[mi][ni] = __builtin_amdgcn_mfma_f32_16x16x32_bf16(
                    af[mi], bfm[ni], accf[mi][ni], 0, 0, 0);
    }

    float s = 0.f;
    #pragma unroll
    for (int mi = 0; mi < 4; ++mi)
        #pragma unroll
        for (int ni = 0; ni < 4; ++ni)
            #pragma unroll
            for (int r = 0; r < 4; ++r)
                s += fabsf(accf[mi][ni][r]);
    #pragma unroll
    for (int off = 32; off > 0; off >>= 1) s += __shfl_down(s, off);
    if (lane == 0) atomicAdd(&acc[2], s);
}

__global__ void final_kernel(const float* __restrict__ acc,
                             float* __restrict__ out) {
    // kp/(B*HW) + desc/(B*C*HW) + match/(B*HW*HW)
    out[0] = acc[0] * (1.0f / 8192.0f)
           + acc[1] * (1.0f / 2097152.0f)
           + acc[2] * (1.0f / 33554432.0f);
}

extern "C" void kernel_launch(void* const* d_in, const int* in_sizes, int n_in,
                              void* d_out, int out_size, void* d_ws, size_t ws_size,
                              hipStream_t stream) {
    const float* sv = (const float*)d_in[0];
    const float* si = (const float*)d_in[1];
    const float* sf = (const float*)d_in[2];
    const float* dv = (const float*)d_in[3];
    const float* di = (const float*)d_in[4];
    const float* df = (const float*)d_in[5];

    unsigned short* Abf = (unsigned short*)d_ws;                       // 4 MB
    unsigned short* Dbf = Abf + (size_t)BB * HWN * CC;                 // 4 MB
    float* acc = (float*)(Dbf + (size_t)BB * HWN * CC);                // 16 B

    zero_acc_kernel<<<1, 64, 0, stream>>>(acc);
    prep_kernel<<<dim3(BB * (HWN / PT)), 256, 0, stream>>>(
        sv, si, sf, dv, di, df, Abf, Dbf, acc);
    gemm_abs_kernel<<<dim3(HWN / 128, HWN / 128, BB), 256, 0, stream>>>(
        Abf, Dbf, acc);
    final_kernel<<<1, 1, 0, stream>>>(acc, (float*)d_out);
}

// Round 2
// 125.151 us; speedup vs baseline: 1.7892x; 1.7892x over previous
//
#include <hip/hip_runtime.h>
#include <hip/hip_bf16.h>
#include <math.h>

// Problem constants: B=2, C=256, H=W=64 -> HW=4096
#define BB 2
#define CC 256
#define HWN 4096
#define PT 32              // pixels per prep block
#define TM 128             // GEMM block tile (M and N)
#define BK 64              // GEMM K staging chunk

typedef __attribute__((ext_vector_type(8))) __bf16 bf16x8;
typedef __attribute__((ext_vector_type(4))) float floatx4;

__device__ __forceinline__ unsigned short f2bf(float f) {
    union { float f; unsigned u; } v; v.f = f;
    unsigned r = v.u + 0x7FFF + ((v.u >> 16) & 1);   // round-to-nearest-even
    return (unsigned short)(r >> 16);
}

__device__ __forceinline__ float bf2f(unsigned short h) {
    union { unsigned u; float f; } v; v.u = ((unsigned)h) << 16;
    return v.f;
}

// async global->LDS, 16B per lane. LDS dest is wave-uniform base + lane*16:
// pass the SAME lds pointer for all lanes of a wave.
__device__ __forceinline__ void load_lds16(const void* g, void* l) {
    __builtin_amdgcn_global_load_lds(
        (const __attribute__((address_space(1))) unsigned int*)g,
        (__attribute__((address_space(3))) unsigned int*)l, 16, 0, 0);
}

// acc[0]=kp_sum, acc[1]=desc_sum, acc[2]=match_sum
__global__ void zero_acc_kernel(float* acc) {
    if (threadIdx.x < 4) acc[threadIdx.x] = 0.0f;
}

// One block per (batch, 32-pixel chunk), 1024 threads (16 waves) for latency
// hiding. Computes per-pixel channel norms, writes A=norm(dv),
// D=norm(df)-norm(di) transposed to [b][pixel][channel] bf16 (K-contiguous
// for MFMA). Fuses desc-loss and kp-loss partial sums.
__global__ __launch_bounds__(1024) void prep_kernel(
    const float* __restrict__ sv, const float* __restrict__ si,
    const float* __restrict__ sf, const float* __restrict__ dv,
    const float* __restrict__ di, const float* __restrict__ df,
    unsigned short* __restrict__ Abf, unsigned short* __restrict__ Dbf,
    float* __restrict__ acc)
{
    __shared__ unsigned short lv[PT][CC];  // 16 KB each; 48 KB total
    __shared__ unsigned short li[PT][CC];
    __shared__ unsigned short lf[PT][CC];
    __shared__ float ssq[3][PT];
    __shared__ float inv[3][PT];
    __shared__ float sdesc;

    const int b   = blockIdx.x / (HWN / PT);
    const int p0  = (blockIdx.x % (HWN / PT)) * PT;
    const int tid = threadIdx.x;
    const int tp  = tid & (PT - 1);   // pixel within chunk
    const int cs  = tid >> 5;         // channel subgroup 0..31 (8 ch each)

    if (tid < 3 * PT) ((float*)ssq)[tid] = 0.0f;
    if (tid == 0) sdesc = 0.0f;
    __syncthreads();

    float sqv = 0.f, sqi = 0.f, sqf = 0.f, descp = 0.f;
    const size_t base = (size_t)b * CC * HWN + p0 + tp;
    #pragma unroll
    for (int j = 0; j < 8; ++j) {
        const int c = cs * 8 + j;
        const size_t idx = base + (size_t)c * HWN;   // coalesced along tp
        const float v = dv[idx], ii = di[idx], ff = df[idx];
        descp += fabsf(ff - 0.5f * (v + ii));
        sqv += v * v; sqi += ii * ii; sqf += ff * ff;
        lv[tp][c] = f2bf(v); li[tp][c] = f2bf(ii); lf[tp][c] = f2bf(ff);
    }
    atomicAdd(&ssq[0][tp], sqv);
    atomicAdd(&ssq[1][tp], sqi);
    atomicAdd(&ssq[2][tp], sqf);

    // desc partial: wave reduce, one LDS atomic per wave
    #pragma unroll
    for (int off = 32; off > 0; off >>= 1) descp += __shfl_down(descp, off);
    if ((tid & 63) == 0) atomicAdd(&sdesc, descp);

    // kp term: this block's 32 pixels (first wave only)
    if (tid < 64) {
        float kpv = 0.f;
        if (tid < PT) {
            const size_t sidx = (size_t)b * HWN + p0 + tid;
            kpv = fabsf(sf[sidx] - fmaxf(sv[sidx], si[sidx]));
        }
        #pragma unroll
        for (int off = 32; off > 0; off >>= 1) kpv += __shfl_down(kpv, off);
        if (tid == 0) atomicAdd(&acc[0], kpv);
    }
    __syncthreads();

    if (tid < 3 * PT) {
        const float s = ((float*)ssq)[tid];
        ((float*)inv)[tid] = 1.0f / fmaxf(sqrtf(s), 1e-12f);
    }
    __syncthreads();

    if (tid == 0) atomicAdd(&acc[1], sdesc);   // one global atomic per block

    // Write phase: 1024 threads sweep 32x256 elements -> 2KB contiguous
    // bf16 stores per instruction (coalesced).
    #pragma unroll
    for (int i = tid; i < PT * CC; i += 1024) {
        const int p = i >> 8, c = i & (CC - 1);
        const size_t orow = ((size_t)b * HWN + p0 + p) * CC + c;
        Abf[orow] = f2bf(bf2f(lv[p][c]) * inv[0][p]);
        Dbf[orow] = f2bf(bf2f(lf[p][c]) * inv[2][p] - bf2f(li[p][c]) * inv[1][p]);
    }
}

// Per batch: S = A_rows · D_rows^T over K=256 (both stored [row][k] bf16).
// m97 structure: 128x128 block tile, BK=64 staged into LDS via
// global_load_lds width=16. LDS layout XOR-swizzled: logical (row r, 16B
// chunk c) stored at r*128 + (c^(r&7))*16 — staging stays lane-contiguous
// (HW requirement) while ds_read spreads 16 rows across all banks (2-way =
// free). 4 waves 2x2, each wave 64x64 = 4x4 MFMA 16x16x32 tiles.
// Epilogue: sum |S| (layout-permutation invariant) -> one atomic per block.
__global__ __launch_bounds__(256) void gemm_abs_kernel(
    const unsigned short* __restrict__ Abf,
    const unsigned short* __restrict__ Dbf,
    float* __restrict__ acc)
{
    __shared__ unsigned short lA[TM * BK];  // 16 KB
    __shared__ unsigned short lB[TM * BK];  // 16 KB
    __shared__ float wsum[4];

    const int b    = blockIdx.z;
    const int bm   = blockIdx.x * TM;
    const int bn   = blockIdx.y * TM;
    const int tid  = threadIdx.x;
    const int wave = tid >> 6;
    const int lane = tid & 63;
    const int wr   = wave >> 1, wc = wave & 1;

    const unsigned short* Ab = Abf + (size_t)b * HWN * CC;
    const unsigned short* Db = Dbf + (size_t)b * HWN * CC;

    const int sr0 = tid >> 3;    // staging row within 32-row group
    const int ss  = tid & 7;     // stored chunk index

    floatx4 accf[4][4];
    #pragma unroll
    for (int mi = 0; mi < 4; ++mi)
        #pragma unroll
        for (int ni = 0; ni < 4; ++ni)
            accf[mi][ni] = (floatx4){0.f, 0.f, 0.f, 0.f};

    for (int k0 = 0; k0 < CC; k0 += BK) {
        __syncthreads();   // previous iteration's reads done before overwrite
        #pragma unroll
        for (int i = 0; i < 4; ++i) {
            const int r  = i * 32 + sr0;
            const int ca = ss ^ (r & 7);                  // logical chunk to fetch
            const size_t gof = (size_t)r * CC + k0 + ca * 8;
            char* ldsA = (char*)lA + (i * 32 + wave * 8) * 128;  // wave-uniform
            char* ldsB = (char*)lB + (i * 32 + wave * 8) * 128;
            load_lds16(Ab + (size_t)bm * CC + gof, ldsA);
            load_lds16(Db + (size_t)bn * CC + gof, ldsB);
        }
        __syncthreads();   // compiler emits vmcnt(0) drain before barrier

        #pragma unroll
        for (int ks = 0; ks < 2; ++ks) {
            const int c = ks * 4 + (lane >> 4);           // logical 16B chunk
            bf16x8 af[4], bfr[4];
            #pragma unroll
            for (int mi = 0; mi < 4; ++mi) {
                const int lr = wr * 64 + mi * 16 + (lane & 15);
                af[mi] = *(const bf16x8*)((const char*)lA
                           + lr * 128 + (c ^ (lr & 7)) * 16);
            }
            #pragma unroll
            for (int ni = 0; ni < 4; ++ni) {
                const int lr = wc * 64 + ni * 16 + (lane & 15);
                bfr[ni] = *(const bf16x8*)((const char*)lB
                           + lr * 128 + (c ^ (lr & 7)) * 16);
            }
            #pragma unroll
            for (int mi = 0; mi < 4; ++mi)
                #pragma unroll
                for (int ni = 0; ni < 4; ++ni)
                    accf[mi][ni] = __builtin_amdgcn_mfma_f32_16x16x32_bf16(
                        af[mi], bfr[ni], accf[mi][ni], 0, 0, 0);
        }
    }

    float s = 0.f;
    #pragma unroll
    for (int mi = 0; mi < 4; ++mi)
        #pragma unroll
        for (int ni = 0; ni < 4; ++ni)
            #pragma unroll
            for (int r = 0; r < 4; ++r)
                s += fabsf(accf[mi][ni][r]);
    #pragma unroll
    for (int off = 32; off > 0; off >>= 1) s += __shfl_down(s, off);
    if (lane == 0) wsum[wave] = s;
    __syncthreads();
    if (tid == 0)
        atomicAdd(&acc[2], wsum[0] + wsum[1] + wsum[2] + wsum[3]);
}

__global__ void final_kernel(const float* __restrict__ acc,
                             float* __restrict__ out) {
    // kp/(B*HW) + desc/(B*C*HW) + match/(B*HW*HW)
    out[0] = acc[0] * (1.0f / 8192.0f)
           + acc[1] * (1.0f / 2097152.0f)
           + acc[2] * (1.0f / 33554432.0f);
}

extern "C" void kernel_launch(void* const* d_in, const int* in_sizes, int n_in,
                              void* d_out, int out_size, void* d_ws, size_t ws_size,
                              hipStream_t stream) {
    const float* sv = (const float*)d_in[0];
    const float* si = (const float*)d_in[1];
    const float* sf = (const float*)d_in[2];
    const float* dv = (const float*)d_in[3];
    const float* di = (const float*)d_in[4];
    const float* df = (const float*)d_in[5];

    unsigned short* Abf = (unsigned short*)d_ws;                       // 4 MB
    unsigned short* Dbf = Abf + (size_t)BB * HWN * CC;                 // 4 MB
    float* acc = (float*)(Dbf + (size_t)BB * HWN * CC);                // 16 B

    zero_acc_kernel<<<1, 64, 0, stream>>>(acc);
    prep_kernel<<<dim3(BB * (HWN / PT)), 1024, 0, stream>>>(
        sv, si, sf, dv, di, df, Abf, Dbf, acc);
    gemm_abs_kernel<<<dim3(HWN / TM, HWN / TM, BB), 256, 0, stream>>>(
        Abf, Dbf, acc);
    final_kernel<<<1, 1, 0, stream>>>(acc, (float*)d_out);
}

// Round 3
// 123.012 us; speedup vs baseline: 1.8203x; 1.0174x over previous
//
#include <hip/hip_runtime.h>
#include <hip/hip_bf16.h>
#include <math.h>

// Problem constants: B=2, C=256, H=W=64 -> HW=4096
#define BB 2
#define CC 256
#define CCP (CC + 2)       // +2 shorts pad: LDS row stride 516B -> bank (tp + c/2)%32, conflict-free transpose stores
#define HWN 4096
#define PT 32              // pixels per prep block
#define TM 128             // GEMM block tile (M and N)
#define BK 64              // GEMM K staging chunk

typedef __attribute__((ext_vector_type(8))) __bf16 bf16x8;
typedef __attribute__((ext_vector_type(4))) float floatx4;

__device__ __forceinline__ unsigned short f2bf(float f) {
    union { float f; unsigned u; } v; v.f = f;
    unsigned r = v.u + 0x7FFF + ((v.u >> 16) & 1);   // round-to-nearest-even
    return (unsigned short)(r >> 16);
}

__device__ __forceinline__ float bf2f(unsigned short h) {
    union { unsigned u; float f; } v; v.u = ((unsigned)h) << 16;
    return v.f;
}

// async global->LDS, 16B per lane. LDS dest is wave-uniform base + lane*16:
// pass the SAME lds pointer for all lanes of a wave.
__device__ __forceinline__ void load_lds16(const void* g, void* l) {
    __builtin_amdgcn_global_load_lds(
        (const __attribute__((address_space(1))) unsigned int*)g,
        (__attribute__((address_space(3))) unsigned int*)l, 16, 0, 0);
}

// acc[0]=kp_sum, acc[1]=desc_sum, acc[2]=match_sum
__global__ void zero_acc_kernel(float* acc) {
    if (threadIdx.x < 4) acc[threadIdx.x] = 0.0f;
}

// One block per (batch, 32-pixel chunk), 1024 threads (16 waves).
// Computes per-pixel channel norms, writes A=norm(dv), D=norm(df)-norm(di)
// transposed to [b][pixel][channel] bf16 (K-contiguous for MFMA). Fuses
// desc-loss and kp-loss partial sums.
__global__ __launch_bounds__(1024) void prep_kernel(
    const float* __restrict__ sv, const float* __restrict__ si,
    const float* __restrict__ sf, const float* __restrict__ dv,
    const float* __restrict__ di, const float* __restrict__ df,
    unsigned short* __restrict__ Abf, unsigned short* __restrict__ Dbf,
    float* __restrict__ acc)
{
    __shared__ unsigned short lv[PT][CCP];  // ~16.1 KB each; ~48.4 KB total
    __shared__ unsigned short li[PT][CCP];
    __shared__ unsigned short lf[PT][CCP];
    __shared__ float ssq[3][PT];
    __shared__ float inv[3][PT];
    __shared__ float sdesc;

    const int b   = blockIdx.x / (HWN / PT);
    const int p0  = (blockIdx.x % (HWN / PT)) * PT;
    const int tid = threadIdx.x;
    const int tp  = tid & (PT - 1);   // pixel within chunk
    const int cs  = tid >> 5;         // channel subgroup 0..31 (8 ch each)

    if (tid < 3 * PT) ((float*)ssq)[tid] = 0.0f;
    if (tid == 0) sdesc = 0.0f;
    __syncthreads();

    float sqv = 0.f, sqi = 0.f, sqf = 0.f, descp = 0.f;
    const size_t base = (size_t)b * CC * HWN + p0 + tp;
    #pragma unroll
    for (int j = 0; j < 8; ++j) {
        const int c = cs * 8 + j;
        const size_t idx = base + (size_t)c * HWN;   // coalesced along tp
        const float v = dv[idx], ii = di[idx], ff = df[idx];
        descp += fabsf(ff - 0.5f * (v + ii));
        sqv += v * v; sqi += ii * ii; sqf += ff * ff;
        lv[tp][c] = f2bf(v); li[tp][c] = f2bf(ii); lf[tp][c] = f2bf(ff);
    }
    // lanes l and l+32 share tp: fold before atomics (halves atomic count)
    sqv += __shfl_down(sqv, 32);
    sqi += __shfl_down(sqi, 32);
    sqf += __shfl_down(sqf, 32);
    if ((tid & 63) < 32) {
        atomicAdd(&ssq[0][tp], sqv);
        atomicAdd(&ssq[1][tp], sqi);
        atomicAdd(&ssq[2][tp], sqf);
    }

    // desc partial: wave reduce, one LDS atomic per wave
    #pragma unroll
    for (int off = 32; off > 0; off >>= 1) descp += __shfl_down(descp, off);
    if ((tid & 63) == 0) atomicAdd(&sdesc, descp);

    // kp term: this block's 32 pixels (first wave only)
    if (tid < 64) {
        float kpv = 0.f;
        if (tid < PT) {
            const size_t sidx = (size_t)b * HWN + p0 + tid;
            kpv = fabsf(sf[sidx] - fmaxf(sv[sidx], si[sidx]));
        }
        #pragma unroll
        for (int off = 32; off > 0; off >>= 1) kpv += __shfl_down(kpv, off);
        if (tid == 0) atomicAdd(&acc[0], kpv);
    }
    __syncthreads();

    if (tid < 3 * PT) {
        const float s = ((float*)ssq)[tid];
        ((float*)inv)[tid] = 1.0f / fmaxf(sqrtf(s), 1e-12f);
    }
    __syncthreads();

    if (tid == 0) atomicAdd(&acc[1], sdesc);   // one global atomic per block

    // Write phase: 1024 threads sweep 32x256 elements -> contiguous bf16
    // stores (coalesced); LDS reads row-contiguous (conflict-free).
    #pragma unroll
    for (int i = tid; i < PT * CC; i += 1024) {
        const int p = i >> 8, c = i & (CC - 1);
        const size_t orow = ((size_t)b * HWN + p0 + p) * CC + c;
        Abf[orow] = f2bf(bf2f(lv[p][c]) * inv[0][p]);
        Dbf[orow] = f2bf(bf2f(lf[p][c]) * inv[2][p] - bf2f(li[p][c]) * inv[1][p]);
    }
}

// Per batch: S = A_rows · D_rows^T over K=256 (both stored [row][k] bf16).
// m97 structure: 128x128 block tile, BK=64 staged into LDS via
// global_load_lds width=16. LDS layout XOR-swizzled: logical (row r, 16B
// chunk c) stored at r*128 + (c^(r&7))*16 — staging stays lane-contiguous
// (HW requirement) while ds_read spreads rows across banks (2-way = free).
// 4 waves 2x2, each wave 64x64 = 4x4 MFMA 16x16x32 tiles.
// Epilogue: sum |S| (layout-permutation invariant) -> one atomic per block.
__global__ __launch_bounds__(256) void gemm_abs_kernel(
    const unsigned short* __restrict__ Abf,
    const unsigned short* __restrict__ Dbf,
    float* __restrict__ acc)
{
    __shared__ unsigned short lA[TM * BK];  // 16 KB
    __shared__ unsigned short lB[TM * BK];  // 16 KB
    __shared__ float wsum[4];

    const int b    = blockIdx.z;
    const int bm   = blockIdx.x * TM;
    const int bn   = blockIdx.y * TM;
    const int tid  = threadIdx.x;
    const int wave = tid >> 6;
    const int lane = tid & 63;
    const int wr   = wave >> 1, wc = wave & 1;

    const unsigned short* Ab = Abf + (size_t)b * HWN * CC;
    const unsigned short* Db = Dbf + (size_t)b * HWN * CC;

    const int sr0 = tid >> 3;    // staging row within 32-row group
    const int ss  = tid & 7;     // stored chunk index

    floatx4 accf[4][4];
    #pragma unroll
    for (int mi = 0; mi < 4; ++mi)
        #pragma unroll
        for (int ni = 0; ni < 4; ++ni)
            accf[mi][ni] = (floatx4){0.f, 0.f, 0.f, 0.f};

    for (int k0 = 0; k0 < CC; k0 += BK) {
        __syncthreads();   // previous iteration's reads done before overwrite
        #pragma unroll
        for (int i = 0; i < 4; ++i) {
            const int r  = i * 32 + sr0;
            const int ca = ss ^ (r & 7);                  // logical chunk to fetch
            const size_t gof = (size_t)r * CC + k0 + ca * 8;
            char* ldsA = (char*)lA + (i * 32 + wave * 8) * 128;  // wave-uniform
            char* ldsB = (char*)lB + (i * 32 + wave * 8) * 128;
            load_lds16(Ab + (size_t)bm * CC + gof, ldsA);
            load_lds16(Db + (size_t)bn * CC + gof, ldsB);
        }
        __syncthreads();   // compiler emits vmcnt(0) drain before barrier

        #pragma unroll
        for (int ks = 0; ks < 2; ++ks) {
            const int c = ks * 4 + (lane >> 4);           // logical 16B chunk
            bf16x8 af[4], bfr[4];
            #pragma unroll
            for (int mi = 0; mi < 4; ++mi) {
                const int lr = wr * 64 + mi * 16 + (lane & 15);
                af[mi] = *(const bf16x8*)((const char*)lA
                           + lr * 128 + (c ^ (lr & 7)) * 16);
            }
            #pragma unroll
            for (int ni = 0; ni < 4; ++ni) {
                const int lr = wc * 64 + ni * 16 + (lane & 15);
                bfr[ni] = *(const bf16x8*)((const char*)lB
                           + lr * 128 + (c ^ (lr & 7)) * 16);
            }
            #pragma unroll
            for (int mi = 0; mi < 4; ++mi)
                #pragma unroll
                for (int ni = 0; ni < 4; ++ni)
                    accf[mi][ni] = __builtin_amdgcn_mfma_f32_16x16x32_bf16(
                        af[mi], bfr[ni], accf[mi][ni], 0, 0, 0);
        }
    }

    float s = 0.f;
    #pragma unroll
    for (int mi = 0; mi < 4; ++mi)
        #pragma unroll
        for (int ni = 0; ni < 4; ++ni)
            #pragma unroll
            for (int r = 0; r < 4; ++r)
                s += fabsf(accf[mi][ni][r]);
    #pragma unroll
    for (int off = 32; off > 0; off >>= 1) s += __shfl_down(s, off);
    if (lane == 0) wsum[wave] = s;
    __syncthreads();
    if (tid == 0)
        atomicAdd(&acc[2], wsum[0] + wsum[1] + wsum[2] + wsum[3]);
}

__global__ void final_kernel(const float* __restrict__ acc,
                             float* __restrict__ out) {
    // kp/(B*HW) + desc/(B*C*HW) + match/(B*HW*HW)
    out[0] = acc[0] * (1.0f / 8192.0f)
           + acc[1] * (1.0f / 2097152.0f)
           + acc[2] * (1.0f / 33554432.0f);
}

extern "C" void kernel_launch(void* const* d_in, const int* in_sizes, int n_in,
                              void* d_out, int out_size, void* d_ws, size_t ws_size,
                              hipStream_t stream) {
    const float* sv = (const float*)d_in[0];
    const float* si = (const float*)d_in[1];
    const float* sf = (const float*)d_in[2];
    const float* dv = (const float*)d_in[3];
    const float* di = (const float*)d_in[4];
    const float* df = (const float*)d_in[5];

    unsigned short* Abf = (unsigned short*)d_ws;                       // 4 MB
    unsigned short* Dbf = Abf + (size_t)BB * HWN * CC;                 // 4 MB
    float* acc = (float*)(Dbf + (size_t)BB * HWN * CC);                // 16 B

    zero_acc_kernel<<<1, 64, 0, stream>>>(acc);
    prep_kernel<<<dim3(BB * (HWN / PT)), 1024, 0, stream>>>(
        sv, si, sf, dv, di, df, Abf, Dbf, acc);
    gemm_abs_kernel<<<dim3(HWN / TM, HWN / TM, BB), 256, 0, stream>>>(
        Abf, Dbf, acc);
    final_kernel<<<1, 1, 0, stream>>>(acc, (float*)d_out);
}

// Round 4
// 95.787 us; speedup vs baseline: 2.3377x; 1.2842x over previous
//
#include <hip/hip_runtime.h>
#include <hip/hip_bf16.h>
#include <math.h>

// Problem constants: B=2, C=256, H=W=64 -> HW=4096
#define BB 2
#define CC 256
#define CCP (CC + 2)       // LDS pad for prep transpose stores
#define HWN 4096
#define PT 32              // pixels per prep block
#define TM 128             // GEMM block tile (M and N)

typedef __attribute__((ext_vector_type(4))) int   intx4;
typedef __attribute__((ext_vector_type(8))) int   intx8;
typedef __attribute__((ext_vector_type(4))) float floatx4;

__device__ __forceinline__ unsigned short f2bf(float f) {
    union { float f; unsigned u; } v; v.f = f;
    unsigned r = v.u + 0x7FFF + ((v.u >> 16) & 1);   // round-to-nearest-even
    return (unsigned short)(r >> 16);
}

__device__ __forceinline__ float bf2f(unsigned short h) {
    union { unsigned u; float f; } v; v.u = ((unsigned)h) << 16;
    return v.f;
}

// async global->LDS, 16B per lane. LDS dest is wave-uniform base + lane*16.
__device__ __forceinline__ void load_lds16(const void* g, void* l) {
    __builtin_amdgcn_global_load_lds(
        (const __attribute__((address_space(1))) unsigned int*)g,
        (__attribute__((address_space(3))) unsigned int*)l, 16, 0, 0);
}

// One block per (batch, 32-pixel chunk), 1024 threads. Computes per-pixel
// channel norms, writes A=norm(dv), D=norm(df)-norm(di) transposed to
// [b][pixel][channel] fp8-e4m3 (K-contiguous for MFMA). Per-block kp/desc
// partial sums to arrays (NO contended global atomics — round-3 lesson:
// same-address atomicAdd serializes ~40cyc each at the owning L2 bank).
__global__ __launch_bounds__(1024) void prep_kernel(
    const float* __restrict__ sv, const float* __restrict__ si,
    const float* __restrict__ sf, const float* __restrict__ dv,
    const float* __restrict__ di, const float* __restrict__ df,
    unsigned char* __restrict__ Af8, unsigned char* __restrict__ Df8,
    float* __restrict__ pk, float* __restrict__ pd)
{
    __shared__ unsigned short lv[PT][CCP];
    __shared__ unsigned short li[PT][CCP];
    __shared__ unsigned short lf[PT][CCP];
    __shared__ float ssq[3][PT];
    __shared__ float inv[3][PT];
    __shared__ float sdesc;

    const int b   = blockIdx.x / (HWN / PT);
    const int p0  = (blockIdx.x % (HWN / PT)) * PT;
    const int tid = threadIdx.x;
    const int tp  = tid & (PT - 1);   // pixel within chunk
    const int cs  = tid >> 5;         // channel subgroup 0..31 (8 ch each)

    if (tid < 3 * PT) ((float*)ssq)[tid] = 0.0f;
    if (tid == 0) sdesc = 0.0f;
    __syncthreads();

    float sqv = 0.f, sqi = 0.f, sqf = 0.f, descp = 0.f;
    const size_t base = (size_t)b * CC * HWN + p0 + tp;
    #pragma unroll
    for (int j = 0; j < 8; ++j) {
        const int c = cs * 8 + j;
        const size_t idx = base + (size_t)c * HWN;   // coalesced along tp
        const float v = dv[idx], ii = di[idx], ff = df[idx];
        descp += fabsf(ff - 0.5f * (v + ii));
        sqv += v * v; sqi += ii * ii; sqf += ff * ff;
        lv[tp][c] = f2bf(v); li[tp][c] = f2bf(ii); lf[tp][c] = f2bf(ff);
    }
    // lanes l and l+32 share tp: fold before LDS atomics
    sqv += __shfl_down(sqv, 32);
    sqi += __shfl_down(sqi, 32);
    sqf += __shfl_down(sqf, 32);
    if ((tid & 63) < 32) {
        atomicAdd(&ssq[0][tp], sqv);
        atomicAdd(&ssq[1][tp], sqi);
        atomicAdd(&ssq[2][tp], sqf);
    }

    // desc partial: wave reduce, one LDS atomic per wave
    #pragma unroll
    for (int off = 32; off > 0; off >>= 1) descp += __shfl_down(descp, off);
    if ((tid & 63) == 0) atomicAdd(&sdesc, descp);

    // kp term: this block's 32 pixels (first wave only)
    if (tid < 64) {
        float kpv = 0.f;
        if (tid < PT) {
            const size_t sidx = (size_t)b * HWN + p0 + tid;
            kpv = fabsf(sf[sidx] - fmaxf(sv[sidx], si[sidx]));
        }
        #pragma unroll
        for (int off = 32; off > 0; off >>= 1) kpv += __shfl_down(kpv, off);
        if (tid == 0) pk[blockIdx.x] = kpv;
    }
    __syncthreads();

    if (tid < 3 * PT) {
        const float s = ((float*)ssq)[tid];
        ((float*)inv)[tid] = 1.0f / fmaxf(sqrtf(s), 1e-12f);
    }
    __syncthreads();

    if (tid == 0) pd[blockIdx.x] = sdesc;

    // Write phase: pack 4 channels per int via v_cvt_pk_fp8_f32 (RNE),
    // coalesced dword stores. 2048 ints / 1024 threads = 2 each.
    int* Ao = (int*)(Af8 + ((size_t)b * HWN + p0) * CC);
    int* Do = (int*)(Df8 + ((size_t)b * HWN + p0) * CC);
    #pragma unroll
    for (int i = tid; i < PT * CC / 4; i += 1024) {
        const int p = i >> 6, c0 = (i & 63) * 4;
        const float ia = inv[0][p], ib = inv[1][p], ic = inv[2][p];
        float a0 = bf2f(lv[p][c0 + 0]) * ia, a1 = bf2f(lv[p][c0 + 1]) * ia;
        float a2 = bf2f(lv[p][c0 + 2]) * ia, a3 = bf2f(lv[p][c0 + 3]) * ia;
        float d0 = bf2f(lf[p][c0 + 0]) * ic - bf2f(li[p][c0 + 0]) * ib;
        float d1 = bf2f(lf[p][c0 + 1]) * ic - bf2f(li[p][c0 + 1]) * ib;
        float d2 = bf2f(lf[p][c0 + 2]) * ic - bf2f(li[p][c0 + 2]) * ib;
        float d3 = bf2f(lf[p][c0 + 3]) * ic - bf2f(li[p][c0 + 3]) * ib;
        int wa = __builtin_amdgcn_cvt_pk_fp8_f32(a0, a1, 0, false);
        wa     = __builtin_amdgcn_cvt_pk_fp8_f32(a2, a3, wa, true);
        int wd = __builtin_amdgcn_cvt_pk_fp8_f32(d0, d1, 0, false);
        wd     = __builtin_amdgcn_cvt_pk_fp8_f32(d2, d3, wd, true);
        Ao[i] = wa;
        Do[i] = wd;
    }
}

// Per batch: S = A_rows · D_rows^T, K=256, fp8-e4m3, MX-scaled MFMA
// (16x16x128, unit scales) -> 2x MFMA rate vs bf16 and only TWO k-steps.
// Whole K staged once into LDS (32KB+32KB), single barrier, no K-loop.
// 4-bit XOR swizzle (16 chunks of 16B per 256B row): staging stays
// lane-contiguous (global_load_lds HW requirement) while ds_read_b128 of
// 16 same-chunk rows spreads across banks (2-way = free).
// Epilogue: |.|-sum (invariant to any output permutation; A/B share the
// lane->k mapping so k-permutations cancel too) -> per-wave partial store.
__global__ __launch_bounds__(256) void gemm_abs_kernel(
    const unsigned char* __restrict__ Af8,
    const unsigned char* __restrict__ Df8,
    float* __restrict__ pg)
{
    __shared__ unsigned char lA[TM * CC];  // 32 KB
    __shared__ unsigned char lB[TM * CC];  // 32 KB

    const int b    = blockIdx.z;
    const int bm   = blockIdx.x * TM;
    const int bn   = blockIdx.y * TM;
    const int tid  = threadIdx.x;
    const int wave = tid >> 6;
    const int lane = tid & 63;
    const int wr   = wave >> 1, wc = wave & 1;

    const unsigned char* Agb = Af8 + (size_t)b * HWN * CC + (size_t)bm * CC;
    const unsigned char* Dgb = Df8 + (size_t)b * HWN * CC + (size_t)bn * CC;

    // Stage all of K: each wave covers rows [wave*32, wave*32+32) of both
    // tiles; one wave-op = 4 rows (64 lanes x 16B). Lane fetches the global
    // chunk that lands swizzled: store-chunk s=lane&15 holds logical chunk
    // s^(r&15).
    #pragma unroll
    for (int i = 0; i < 8; ++i) {
        const int r0 = wave * 32 + i * 4;
        const int r  = r0 + (lane >> 4);
        const int cs = (lane & 15) ^ (r & 15);
        const size_t gof = (size_t)r * CC + cs * 16;
        load_lds16(Agb + gof, (char*)lA + r0 * CC);
        load_lds16(Dgb + gof, (char*)lB + r0 * CC);
    }
    __syncthreads();   // vmcnt(0) drain: all staging visible

    floatx4 accf[4][4];
    #pragma unroll
    for (int mi = 0; mi < 4; ++mi)
        #pragma unroll
        for (int ni = 0; ni < 4; ++ni)
            accf[mi][ni] = (floatx4){0.f, 0.f, 0.f, 0.f};

    #pragma unroll
    for (int ks = 0; ks < 2; ++ks) {
        const int cb = ks * 8 + (lane >> 4) * 2;   // logical 16B chunk pair
        intx8 a8[4], b8[4];
        #pragma unroll
        for (int mi = 0; mi < 4; ++mi) {
            const int m = wr * 64 + mi * 16 + (lane & 15);
            const char* pa = (const char*)lA + m * CC;
            intx4 lo = *(const intx4*)(pa + ((cb    ) ^ (m & 15)) * 16);
            intx4 hi = *(const intx4*)(pa + ((cb + 1) ^ (m & 15)) * 16);
            a8[mi] = __builtin_shufflevector(lo, hi, 0, 1, 2, 3, 4, 5, 6, 7);
        }
        #pragma unroll
        for (int ni = 0; ni < 4; ++ni) {
            const int n = wc * 64 + ni * 16 + (lane & 15);
            const char* pb = (const char*)lB + n * CC;
            intx4 lo = *(const intx4*)(pb + ((cb    ) ^ (n & 15)) * 16);
            intx4 hi = *(const intx4*)(pb + ((cb + 1) ^ (n & 15)) * 16);
            b8[ni] = __builtin_shufflevector(lo, hi, 0, 1, 2, 3, 4, 5, 6, 7);
        }
        #pragma unroll
        for (int mi = 0; mi < 4; ++mi)
            #pragma unroll
            for (int ni = 0; ni < 4; ++ni)
                accf[mi][ni] = __builtin_amdgcn_mfma_scale_f32_16x16x128_f8f6f4(
                    a8[mi], b8[ni], accf[mi][ni],
                    0, 0,                      // cbsz=fp8, blgp=fp8
                    0, 0x7F7F7F7F,             // A scales: E8M0 1.0
                    0, 0x7F7F7F7F);            // B scales: E8M0 1.0
    }

    float s = 0.f;
    #pragma unroll
    for (int mi = 0; mi < 4; ++mi)
        #pragma unroll
        for (int ni = 0; ni < 4; ++ni)
            #pragma unroll
            for (int r = 0; r < 4; ++r)
                s += fabsf(accf[mi][ni][r]);
    #pragma unroll
    for (int off = 32; off > 0; off >>= 1) s += __shfl_down(s, off);
    if (lane == 0) {
        const int flat = blockIdx.x + 32 * (blockIdx.y + 32 * blockIdx.z);
        pg[flat * 4 + wave] = s;   // per-wave partial, zero contention
    }
}

// Single block: reduce 8192 match partials + 256 kp + 256 desc partials.
__global__ __launch_bounds__(256) void final_kernel(
    const float* __restrict__ pg, const float* __restrict__ pk,
    const float* __restrict__ pd, float* __restrict__ out)
{
    __shared__ float ws[4];
    const int t = threadIdx.x;
    float s = 0.f;
    #pragma unroll
    for (int i = 0; i < 32; ++i)
        s += pg[t + i * 256];
    s *= (1.0f / 33554432.0f);                 // match / (B*HW*HW)
    s += pk[t] * (1.0f / 8192.0f)              // kp / (B*HW)
       + pd[t] * (1.0f / 2097152.0f);          // desc / (B*C*HW)
    #pragma unroll
    for (int off = 32; off > 0; off >>= 1) s += __shfl_down(s, off);
    if ((t & 63) == 0) ws[t >> 6] = s;
    __syncthreads();
    if (t == 0) out[0] = ws[0] + ws[1] + ws[2] + ws[3];
}

extern "C" void kernel_launch(void* const* d_in, const int* in_sizes, int n_in,
                              void* d_out, int out_size, void* d_ws, size_t ws_size,
                              hipStream_t stream) {
    const float* sv = (const float*)d_in[0];
    const float* si = (const float*)d_in[1];
    const float* sf = (const float*)d_in[2];
    const float* dv = (const float*)d_in[3];
    const float* di = (const float*)d_in[4];
    const float* df = (const float*)d_in[5];

    unsigned char* Af8 = (unsigned char*)d_ws;                 // 2 MB
    unsigned char* Df8 = Af8 + (size_t)BB * HWN * CC;          // 2 MB
    float* pg = (float*)(Df8 + (size_t)BB * HWN * CC);         // 32 KB (8192)
    float* pk = pg + 8192;                                     // 1 KB (256)
    float* pd = pk + 256;                                      // 1 KB (256)

    prep_kernel<<<dim3(BB * (HWN / PT)), 1024, 0, stream>>>(
        sv, si, sf, dv, di, df, Af8, Df8, pk, pd);
    gemm_abs_kernel<<<dim3(HWN / TM, HWN / TM, BB), 256, 0, stream>>>(
        Af8, Df8, pg);
    final_kernel<<<1, 256, 0, stream>>>(pg, pk, pd, (float*)d_out);
}